// Round 7
// baseline (729.301 us; speedup 1.0000x reference)
//
#include <hip/hip_runtime.h>
#include <hip/hip_cooperative_groups.h>

namespace cg = cooperative_groups;

// out = softmax(out_state @ W @ history^T, axis=-1); bias drops out of softmax.
// STATE_LEN=2048, SEQ_LEN=4096, HIDDEN=2048, fp32 in/out.
// Precision: split-bf16 (hi+lo), 3-term MFMA (hh+hl+lh) -> ~4e-3 absmax.
//
// R17: ONE cooperative kernel. Accounting showed ~65-70us of the 272 total
// was inter-kernel launch/sync overhead (sum of modeled stages ~202us), and
// a previous session directly measured ~70us of gaps. Fuse all 5 stages into
// a single hipLaunchCooperativeKernel dispatch (256 blocks x 512 thr, 128KiB
// LDS -> exactly 1 block/CU) with __threadfence()+grid.sync() between
// stages. GEMM body = R16's verbatim (best measured: 93.5us GEMM2, 0 bank
// conflicts, counted vmcnt(8), XCD chunked swizzle). Buffer aliasing
// unchanged; every cross-stage dependency crosses a device fence + barrier.

#define STATE_LEN 2048
#define SEQ_LEN   4096
#define HIDDEN    2048

#define BK 32

// gfx9 s_waitcnt imm: vmcnt[3:0]=b3:0,[5:4]=b15:14; exp=b6:4; lgkm=b11:8
#define WAIT_VM8   0x0F78  // vmcnt(8),  lgkm=15, exp=7
#define WAIT_VM0   0x0F70  // vmcnt(0),  lgkm=15, exp=7
#define WAIT_LGKM0 0xC07F  // lgkmcnt(0), vmcnt=63, exp=7

typedef __bf16 bf16x8 __attribute__((ext_vector_type(8)));
typedef float f32x4 __attribute__((ext_vector_type(4)));

__device__ __forceinline__ unsigned short f32_to_bf16(float f) {
  unsigned u = __float_as_uint(f);
  u += 0x7FFFu + ((u >> 16) & 1u);   // round-to-nearest-even
  return (unsigned short)(u >> 16);
}
__device__ __forceinline__ float bf16_to_f32(unsigned short h) {
  return __uint_as_float(((unsigned)h) << 16);
}

__device__ __forceinline__ void gld16(const void* g, void* l) {
  __builtin_amdgcn_global_load_lds(
      (const __attribute__((address_space(1))) unsigned int*)g,
      (__attribute__((address_space(3))) unsigned int*)l,
      16, 0, 0);
}

__device__ __forceinline__ void split8(const float* __restrict__ in,
                                       unsigned short* __restrict__ hi,
                                       unsigned short* __restrict__ lo, int i) {
#pragma unroll
  for (int half = 0; half < 2; ++half) {
    float4 v = *(const float4*)&in[i + half * 4];
    ushort4 h, l;
    h.x = f32_to_bf16(v.x); l.x = f32_to_bf16(v.x - bf16_to_f32(h.x));
    h.y = f32_to_bf16(v.y); l.y = f32_to_bf16(v.y - bf16_to_f32(h.y));
    h.z = f32_to_bf16(v.z); l.z = f32_to_bf16(v.z - bf16_to_f32(h.z));
    h.w = f32_to_bf16(v.w); l.w = f32_to_bf16(v.w - bf16_to_f32(h.w));
    *(ushort4*)&hi[i + half * 4] = h;
    *(ushort4*)&lo[i + half * 4] = l;
  }
}

// -------- 256x256 split-bf16 GEMM stage, C[m][n] = sum_k A[m][k]*B[n][k] ----
// R16 body verbatim: 8 waves (4Mx2N), wave tile 64x128 (4x8 frags of
// 16x16x32), BK=32, dbuf LDS 128 KiB. LDS swizzle: slot (row,c) holds chunk
// c^((r>>1)&3) via pre-swizzled global source (measured: 0 bank conflicts).
// Raw s_barrier + counted vmcnt(8): next tile's 8 DMAs in flight across the
// whole MFMA block.
__device__ __forceinline__ void gemm_stage(
    const unsigned short* __restrict__ Ahi, const unsigned short* __restrict__ Alo,
    const unsigned short* __restrict__ Bhi, const unsigned short* __restrict__ Blo,
    float* __restrict__ Cf, int tileM, int tileN, int kBase, int iters,
    int N, int K,
    unsigned short (*sA)[2][256 * BK], unsigned short (*sB)[2][256 * BK]) {
  const int t = threadIdx.x;           // 0..511 (8 waves)
  const int rr = t >> 2;               // staging row within a 128-row group
  const int cc = t & 3;                // fixed LDS 16B-slot index

  const int lane = t & 63;
  const int wave = t >> 6;
  const int wm = wave >> 1;            // 4x2 wave grid, wave tile 64x128
  const int wn = wave & 1;
  const int lr = lane & 15;
  const int kqc = lane >> 4;           // fragment k-chunk (16B units)

  f32x4 acc[4][8] = {};

  auto stage = [&](int buf, int k0) {
#pragma unroll
    for (int p = 0; p < 2; ++p) {
      const int r = p * 128 + rr;
      const int q = cc ^ ((r >> 1) & 3);  // swizzle via global addr
      const size_t ga = (size_t)(tileM + r) * K + k0 + q * 8;
      const size_t gb = (size_t)(tileN + r) * K + k0 + q * 8;
      const int ls = r * BK + cc * 8;     // == wave_base + lane*16 bytes
      gld16(Ahi + ga, &sA[buf][0][ls]);
      gld16(Alo + ga, &sA[buf][1][ls]);
      gld16(Bhi + gb, &sB[buf][0][ls]);
      gld16(Blo + gb, &sB[buf][1][ls]);
    }
  };

  stage(0, kBase);

  for (int it = 0; it < iters; ++it) {
    const int buf = it & 1;

    if (it + 1 < iters) {
      stage(buf ^ 1, kBase + (it + 1) * BK);
      __builtin_amdgcn_s_waitcnt(WAIT_VM8);  // oldest 8 (= this tile) done
    } else {
      __builtin_amdgcn_s_waitcnt(WAIT_VM0);
    }
    __builtin_amdgcn_s_barrier();            // all waves staged buf

    bf16x8 ah[4], al[4];
#pragma unroll
    for (int mi = 0; mi < 4; ++mi) {
      const int R = wm * 64 + mi * 16 + lr;
      const int off = R * BK + (kqc ^ ((R >> 1) & 3)) * 8;
      ah[mi] = *(const bf16x8*)&sA[buf][0][off];
      al[mi] = *(const bf16x8*)&sA[buf][1][off];
    }
#pragma unroll
    for (int nh = 0; nh < 2; ++nh) {
      bf16x8 bh[4], bl[4];
#pragma unroll
      for (int nj = 0; nj < 4; ++nj) {
        const int R = wn * 128 + (nh * 4 + nj) * 16 + lr;
        const int off = R * BK + (kqc ^ ((R >> 1) & 3)) * 8;
        bh[nj] = *(const bf16x8*)&sB[buf][0][off];
        bl[nj] = *(const bf16x8*)&sB[buf][1][off];
      }
#pragma unroll
      for (int mi = 0; mi < 4; ++mi)
#pragma unroll
        for (int nj = 0; nj < 4; ++nj) {
          f32x4 a = acc[mi][nh * 4 + nj];
          a = __builtin_amdgcn_mfma_f32_16x16x32_bf16(ah[mi], bh[nj], a, 0, 0, 0);
          a = __builtin_amdgcn_mfma_f32_16x16x32_bf16(ah[mi], bl[nj], a, 0, 0, 0);
          a = __builtin_amdgcn_mfma_f32_16x16x32_bf16(al[mi], bh[nj], a, 0, 0, 0);
          acc[mi][nh * 4 + nj] = a;
        }
    }

    __builtin_amdgcn_s_waitcnt(WAIT_LGKM0);  // frag reads landed in regs
    __builtin_amdgcn_s_barrier();            // safe to overwrite buf next iter
  }

  // epilogue: C/D layout col=lane&15, row=(lane>>4)*4+reg
#pragma unroll
  for (int mi = 0; mi < 4; ++mi)
#pragma unroll
    for (int ni = 0; ni < 8; ++ni)
#pragma unroll
      for (int e = 0; e < 4; ++e) {
        const int row = tileM + wm * 64 + mi * 16 + (lane >> 4) * 4 + e;
        const int col = tileN + wn * 128 + ni * 16 + lr;
        Cf[(size_t)row * N + col] = acc[mi][ni][e];
      }
}

// ------------------------- the fused cooperative kernel ---------------------
__global__ __launch_bounds__(512, 2) void fused_all(
    const float* __restrict__ os, const float* __restrict__ hist,
    const float* __restrict__ W,
    unsigned short* __restrict__ ohi, unsigned short* __restrict__ olo,
    unsigned short* __restrict__ hhi, unsigned short* __restrict__ hlo,
    unsigned short* __restrict__ wthi, unsigned short* __restrict__ wtlo,
    float* __restrict__ g1p0, float* __restrict__ g1p1,
    float* __restrict__ g1p2, float* __restrict__ g1p3,
    unsigned short* __restrict__ thi, unsigned short* __restrict__ tlo,
    float* __restrict__ out, float* __restrict__ p1out) {
  __shared__ __align__(16) unsigned short sA[2][2][256 * BK];  // 64 KB
  __shared__ __align__(16) unsigned short sB[2][2][256 * BK];  // 64 KB

  cg::grid_group grid = cg::this_grid();
  const int t = threadIdx.x;           // 0..511
  const int b = blockIdx.x;            // 0..255
  const int gtid = b * 512 + t;        // 0..131071

  // ========== stage A: pack (W transpose + os/hist splits) ==========
  {
    // W transpose: 2 half-blocks x 2 reps = 1024 64x64 tiles total.
    const int h = t >> 8;              // half-block 0/1
    const int tt = t & 255;
    float (*tile)[65] = (float(*)[65])((char*)sA + h * 32768);  // 16.6KB each
    const int lr = tt >> 4;
    const int c4 = (tt & 15) * 4;
#pragma unroll
    for (int rep = 0; rep < 2; ++rep) {
      const int bt = (b * 2 + h) * 2 + rep;   // 0..1023
      const int h0 = (bt & 31) * 64;          // W row base
      const int k0 = (bt >> 5) * 64;          // W col base
      __syncthreads();                        // tile reuse across reps
#pragma unroll
      for (int pass = 0; pass < 4; ++pass) {
        const int row = pass * 16 + lr;
        float4 v = *(const float4*)&W[(size_t)(h0 + row) * HIDDEN + k0 + c4];
        tile[row][c4] = v.x; tile[row][c4 + 1] = v.y;
        tile[row][c4 + 2] = v.z; tile[row][c4 + 3] = v.w;
      }
      __syncthreads();
#pragma unroll
      for (int pass = 0; pass < 4; ++pass) {
        const int kl = pass * 16 + (tt >> 4);
        const int hl = (tt & 15) * 4;
        ushort4 h4, l4;
#pragma unroll
        for (int j = 0; j < 4; ++j) {
          const float x = tile[hl + j][kl];
          const unsigned short hh = f32_to_bf16(x);
          ((unsigned short*)&h4)[j] = hh;
          ((unsigned short*)&l4)[j] = f32_to_bf16(x - bf16_to_f32(hh));
        }
        const size_t o = (size_t)(k0 + kl) * HIDDEN + h0 + hl;
        *(ushort4*)&wthi[o] = h4;
        *(ushort4*)&wtlo[o] = l4;
      }
    }
    // splits (grid-stride, 8 floats per unit)
    for (int u = gtid; u < (STATE_LEN * HIDDEN) / 8; u += 131072)
      split8(os, ohi, olo, u * 8);
    for (int u = gtid; u < (SEQ_LEN * HIDDEN) / 8; u += 131072)
      split8(hist, hhi, hlo, u * 8);
  }
  __threadfence();
  grid.sync();

  // ========== stage B: GEMM1  T-partials = os @ Wt  (8x8x4) ==========
  {
    int flat = (b & 7) * 32 + (b >> 3);       // XCD chunked swizzle
    const int nbx = flat & 7;
    const int nby = (flat >> 3) & 7;
    const int nbz = flat >> 6;                // 0..3
    float* Cf = (nbz == 0) ? g1p0 : (nbz == 1) ? g1p1 : (nbz == 2) ? g1p2 : g1p3;
    gemm_stage(ohi, olo, wthi, wtlo, Cf, nby * 256, nbx * 256, nbz * 512, 16,
               HIDDEN, HIDDEN, sA, sB);
  }
  __threadfence();
  grid.sync();

  // ========== stage C: T = p0+p1+p2+p3 -> split bf16 ==========
  {
    const int n4 = (STATE_LEN * HIDDEN) / 4;  // float4 units
    for (int u = gtid; u < n4; u += 131072) {
      const int i = u * 4;
      float4 a = *(const float4*)&g1p0[i];
      float4 bb = *(const float4*)&g1p1[i];
      float4 c = *(const float4*)&g1p2[i];
      float4 d = *(const float4*)&g1p3[i];
      a.x = (a.x + bb.x) + (c.x + d.x);
      a.y = (a.y + bb.y) + (c.y + d.y);
      a.z = (a.z + bb.z) + (c.z + d.z);
      a.w = (a.w + bb.w) + (c.w + d.w);
      ushort4 h, l;
      h.x = f32_to_bf16(a.x); l.x = f32_to_bf16(a.x - bf16_to_f32(h.x));
      h.y = f32_to_bf16(a.y); l.y = f32_to_bf16(a.y - bf16_to_f32(h.y));
      h.z = f32_to_bf16(a.z); l.z = f32_to_bf16(a.z - bf16_to_f32(h.z));
      h.w = f32_to_bf16(a.w); l.w = f32_to_bf16(a.w - bf16_to_f32(h.w));
      *(ushort4*)&thi[i] = h;
      *(ushort4*)&tlo[i] = l;
    }
  }
  __threadfence();
  grid.sync();

  // ========== stage D: GEMM2  scores-partials = T @ hist^T  (16x8x2) ==========
  {
    int flat = (b & 7) * 32 + (b >> 3);       // XCD chunked swizzle
    const int nbx = flat & 15;
    const int q = flat >> 4;
    const int nby = q & 7;
    const int nbz = q >> 3;                   // 0..1
    float* Cf = (nbz == 0) ? out : p1out;
    gemm_stage(thi, tlo, hhi, hlo, Cf, nby * 256, nbx * 256, nbz * 1024, 32,
               SEQ_LEN, HIDDEN, sA, sB);
  }
  __threadfence();
  grid.sync();

  // ========== stage E: row softmax (fusing the z-partial add), 8 rows/blk ====
  {
    float* sred = (float*)&sB[0][0][0];       // sB dead after stage D
    const int lane = t & 63;
    const int wave = t >> 6;                  // 0..7
    for (int rr = 0; rr < 8; ++rr) {
      __syncthreads();                        // sred reuse across rows
      const int row = b * 8 + rr;
      float* p = out + (size_t)row * SEQ_LEN;
      const float* q = p1out + (size_t)row * SEQ_LEN;
      const int base = t * 8;

      float4 v[2];
      float m = -3.0e38f;
#pragma unroll
      for (int k = 0; k < 2; ++k) {
        float4 a = *(const float4*)&p[base + k * 4];
        float4 bb = *(const float4*)&q[base + k * 4];
        a.x += bb.x; a.y += bb.y; a.z += bb.z; a.w += bb.w;
        v[k] = a;
        m = fmaxf(m, fmaxf(fmaxf(a.x, a.y), fmaxf(a.z, a.w)));
      }
#pragma unroll
      for (int off = 32; off > 0; off >>= 1) m = fmaxf(m, __shfl_xor(m, off, 64));
      if (lane == 0) sred[wave] = m;
      __syncthreads();
      m = sred[0];
#pragma unroll
      for (int w = 1; w < 8; ++w) m = fmaxf(m, sred[w]);

      float s = 0.f;
#pragma unroll
      for (int k = 0; k < 2; ++k) {
        v[k].x = __expf(v[k].x - m);
        v[k].y = __expf(v[k].y - m);
        v[k].z = __expf(v[k].z - m);
        v[k].w = __expf(v[k].w - m);
        s += (v[k].x + v[k].y) + (v[k].z + v[k].w);
      }
#pragma unroll
      for (int off = 32; off > 0; off >>= 1) s += __shfl_xor(s, off, 64);
      __syncthreads();                        // all reads of sred (max) done
      if (lane == 0) sred[wave] = s;
      __syncthreads();
      s = ((sred[0] + sred[1]) + (sred[2] + sred[3])) +
          ((sred[4] + sred[5]) + (sred[6] + sred[7]));
      const float inv = 1.0f / s;
#pragma unroll
      for (int k = 0; k < 2; ++k) {
        v[k].x *= inv; v[k].y *= inv; v[k].z *= inv; v[k].w *= inv;
        *(float4*)&p[base + k * 4] = v[k];
      }
    }
  }
}

extern "C" void kernel_launch(void* const* d_in, const int* in_sizes, int n_in,
                              void* d_out, int out_size, void* d_ws, size_t ws_size,
                              hipStream_t stream) {
  const float* out_state = (const float*)d_in[0];  // [2048, 2048]
  const float* history   = (const float*)d_in[1];  // [4096, 2048]
  const float* W         = (const float*)d_in[2];  // [2048, 2048]
  // d_in[3] = b : softmax-invariant, unused.
  float* out = (float*)d_out;                      // [2048, 4096] fp32

  char* ws = (char*)d_ws;
  const size_t MB = 1ull << 20;
  unsigned short* ohi  = (unsigned short*)(ws + 0 * MB);   // 8 MB
  unsigned short* olo  = (unsigned short*)(ws + 8 * MB);   // 8 MB
  unsigned short* wthi = (unsigned short*)(ws + 16 * MB);  // 8 MB
  unsigned short* wtlo = (unsigned short*)(ws + 24 * MB);  // 8 MB
  unsigned short* hhi  = (unsigned short*)(ws + 32 * MB);  // 16 MB
  unsigned short* hlo  = (unsigned short*)(ws + 48 * MB);  // 16 MB
  float*          pws  = (float*)(ws + 64 * MB);           // 32 MB fp32 partials

  const size_t QSZ = (size_t)STATE_LEN * HIDDEN;           // 4M elems = 16 MB
  // GEMM1 partials: 2 in ws, 2 in d_out (d_out dead until GEMM2)
  float* g1p0 = pws;
  float* g1p1 = pws + QSZ;
  float* g1p2 = out;
  float* g1p3 = out + QSZ;
  // T split reuses ws[0:16] (os split dead after GEMM1); GEMM2 z=1 partial
  // reuses pws (GEMM1 ws-partials dead after reduce).
  unsigned short* thi = (unsigned short*)(ws + 0 * MB);
  unsigned short* tlo = (unsigned short*)(ws + 8 * MB);
  float* p1out = pws;

  void* args[] = {
      (void*)&out_state, (void*)&history, (void*)&W,
      (void*)&ohi, (void*)&olo, (void*)&hhi, (void*)&hlo,
      (void*)&wthi, (void*)&wtlo,
      (void*)&g1p0, (void*)&g1p1, (void*)&g1p2, (void*)&g1p3,
      (void*)&thi, (void*)&tlo, (void*)&out, (void*)&p1out};
  hipLaunchCooperativeKernel(reinterpret_cast<void*>(fused_all), dim3(256),
                             dim3(512), args, 0, stream);
}

// Round 9
// 272.356 us; speedup vs baseline: 2.6777x; 2.6777x over previous
//
#include <hip/hip_runtime.h>

// out = softmax(out_state @ W @ history^T, axis=-1); bias drops out of softmax.
// STATE_LEN=2048, SEQ_LEN=4096, HIDDEN=2048, fp32 in/out.
// Precision: split-bf16 (hi+lo), 3-term MFMA (hh+hl+lh) -> ~4e-3 absmax.
//
// R18 (resubmit; R8 bench was an infra failure, kernel never ran): back to
// the proven 5-kernel pipeline (R17 proved the ~75us "gap" is FIXED harness
// overhead, not launch cost -- fusion abandoned). GEMM change: just-in-time
// fragment reads. Cycle model showed iter time = MFMA(3725) + LDS reads
// (2304) + DMA(512) SUMMED: after each barrier all 8 waves burst 16 reads
// before their first MFMA, LDS round-robins, so every wave's reads land late
// together -> matrix pipe idles during reads, LDS idles during MFMAs. Fix:
// program-order reads in small just-in-time groups (6 b128 before first MFMA
// group, rest interleaved; register B double-buffer, 4 reads per 12 MFMAs).
// Pure reordering: same instr count, same barriers.

#define STATE_LEN 2048
#define SEQ_LEN   4096
#define HIDDEN    2048

#define BK 32

// gfx9 s_waitcnt imm: vmcnt[3:0]=b3:0,[5:4]=b15:14; exp=b6:4; lgkm=b11:8
#define WAIT_VM8   0x0F78  // vmcnt(8),  lgkm=15, exp=7
#define WAIT_VM0   0x0F70  // vmcnt(0),  lgkm=15, exp=7
#define WAIT_LGKM0 0xC07F  // lgkmcnt(0), vmcnt=63, exp=7

typedef __bf16 bf16x8 __attribute__((ext_vector_type(8)));
typedef float f32x4 __attribute__((ext_vector_type(4)));

__device__ __forceinline__ unsigned short f32_to_bf16(float f) {
  unsigned u = __float_as_uint(f);
  u += 0x7FFFu + ((u >> 16) & 1u);   // round-to-nearest-even
  return (unsigned short)(u >> 16);
}
__device__ __forceinline__ float bf16_to_f32(unsigned short h) {
  return __uint_as_float(((unsigned)h) << 16);
}

__device__ __forceinline__ void gld16(const void* g, void* l) {
  __builtin_amdgcn_global_load_lds(
      (const __attribute__((address_space(1))) unsigned int*)g,
      (__attribute__((address_space(3))) unsigned int*)l,
      16, 0, 0);
}

// ---------------- fused pack: W-transpose FIRST, then splits ----------------
// jobs by flat blockIdx.x:
//   [0,1024)      : transpose+split W, 64x64 tile per block (longest -> first)
//   [1024,3072)   : split out_state (4M elems, 2048 elems/block, 32B/thread)
//   [3072,7168)   : split history   (8M elems)
__global__ __launch_bounds__(256) void pack_all(
    const float* __restrict__ os, const float* __restrict__ hist,
    const float* __restrict__ W,
    unsigned short* __restrict__ ohi, unsigned short* __restrict__ olo,
    unsigned short* __restrict__ hhi, unsigned short* __restrict__ hlo,
    unsigned short* __restrict__ wthi, unsigned short* __restrict__ wtlo) {
  const int bx = blockIdx.x;
  const int t = threadIdx.x;
  if (bx >= 1024) {
    const int b2 = bx - 1024;
    const float* in;
    unsigned short *hi, *lo;
    int i;
    if (b2 < 2048) {
      in = os; hi = ohi; lo = olo; i = (b2 * 256 + t) * 8;
    } else {
      in = hist; hi = hhi; lo = hlo; i = ((b2 - 2048) * 256 + t) * 8;
    }
#pragma unroll
    for (int half = 0; half < 2; ++half) {
      float4 v = *(const float4*)&in[i + half * 4];
      ushort4 h, l;
      h.x = f32_to_bf16(v.x); l.x = f32_to_bf16(v.x - bf16_to_f32(h.x));
      h.y = f32_to_bf16(v.y); l.y = f32_to_bf16(v.y - bf16_to_f32(h.y));
      h.z = f32_to_bf16(v.z); l.z = f32_to_bf16(v.z - bf16_to_f32(h.z));
      h.w = f32_to_bf16(v.w); l.w = f32_to_bf16(v.w - bf16_to_f32(h.w));
      *(ushort4*)&hi[i + half * 4] = h;
      *(ushort4*)&lo[i + half * 4] = l;
    }
  } else {
    // transpose 64x64 tile: Wt[k][h] = W[h][k]
    __shared__ float tile[64][65];
    const int bt = bx;                  // 32x32 tiles
    const int h0 = (bt & 31) * 64;      // W row base
    const int k0 = (bt >> 5) * 64;      // W col base
    const int lr = t >> 4;
    const int c4 = (t & 15) * 4;
#pragma unroll
    for (int pass = 0; pass < 4; ++pass) {
      const int row = pass * 16 + lr;
      float4 v = *(const float4*)&W[(size_t)(h0 + row) * HIDDEN + k0 + c4];
      tile[row][c4] = v.x; tile[row][c4 + 1] = v.y;
      tile[row][c4 + 2] = v.z; tile[row][c4 + 3] = v.w;
    }
    __syncthreads();
#pragma unroll
    for (int pass = 0; pass < 4; ++pass) {
      const int kl = pass * 16 + (t >> 4);
      const int hl = (t & 15) * 4;
      ushort4 h4, l4;
#pragma unroll
      for (int j = 0; j < 4; ++j) {
        const float x = tile[hl + j][kl];
        const unsigned short h = f32_to_bf16(x);
        ((unsigned short*)&h4)[j] = h;
        ((unsigned short*)&l4)[j] = f32_to_bf16(x - bf16_to_f32(h));
      }
      const size_t o = (size_t)(k0 + kl) * HIDDEN + h0 + hl;
      *(ushort4*)&wthi[o] = h4;
      *(ushort4*)&wtlo[o] = l4;
    }
  }
}

// ---- p0+p1+p2+p3 -> split bf16 (hi/lo) ----
__global__ __launch_bounds__(256) void reduce_split4(
    const float* __restrict__ p0, const float* __restrict__ p1,
    const float* __restrict__ p2, const float* __restrict__ p3,
    unsigned short* __restrict__ hi, unsigned short* __restrict__ lo, int n) {
  int i = (blockIdx.x * 256 + threadIdx.x) * 4;
  if (i >= n) return;
  float4 a = *(const float4*)&p0[i];
  float4 b = *(const float4*)&p1[i];
  float4 c = *(const float4*)&p2[i];
  float4 d = *(const float4*)&p3[i];
  a.x = (a.x + b.x) + (c.x + d.x);
  a.y = (a.y + b.y) + (c.y + d.y);
  a.z = (a.z + b.z) + (c.z + d.z);
  a.w = (a.w + b.w) + (c.w + d.w);
  ushort4 h, l;
  h.x = f32_to_bf16(a.x); l.x = f32_to_bf16(a.x - bf16_to_f32(h.x));
  h.y = f32_to_bf16(a.y); l.y = f32_to_bf16(a.y - bf16_to_f32(h.y));
  h.z = f32_to_bf16(a.z); l.z = f32_to_bf16(a.z - bf16_to_f32(h.z));
  h.w = f32_to_bf16(a.w); l.w = f32_to_bf16(a.w - bf16_to_f32(h.w));
  *(ushort4*)&hi[i] = h;
  *(ushort4*)&lo[i] = l;
}

// -------- 256x256 split-bf16 GEMM, C[m][n] = sum_k A[m][k]*B[n][k] --------
// 8 waves (4Mx2N), wave tile 64x128 (4x8 frags of 16x16x32), BK=32, dbuf LDS
// 128 KiB, 1 block/CU. LDS swizzle: slot (row,c) holds chunk c^((r>>1)&3)
// via pre-swizzled global source (measured: 0 bank conflicts). Raw s_barrier
// + counted vmcnt(8). Consume side: just-in-time frag reads (see header).
// KSPLIT>1: (post-swizzle) z selects fp32 partial buffer P0..P3.
template <int KSPLIT>
__global__ __launch_bounds__(512, 2) void gemm_big(
    const unsigned short* __restrict__ Ahi, const unsigned short* __restrict__ Alo,
    const unsigned short* __restrict__ Bhi, const unsigned short* __restrict__ Blo,
    float* __restrict__ P0, float* __restrict__ P1,
    float* __restrict__ P2, float* __restrict__ P3,
    int M, int N, int K) {
  __shared__ __align__(16) unsigned short sA[2][2][256 * BK];  // [buf][hi/lo] 64KB
  __shared__ __align__(16) unsigned short sB[2][2][256 * BK];  // 64KB

  const int t = threadIdx.x;           // 0..511 (8 waves)

  // T1: bijective chunked XCD swizzle (256 blocks, %8==0): XCD c gets 32
  // consecutive tile ids -> z-locality + contiguous A-panel reuse in its L2.
  const int gx = gridDim.x, gy = gridDim.y;
  int flat = blockIdx.x + gx * (blockIdx.y + gy * blockIdx.z);
  const int cpx = (gx * gy * gridDim.z) >> 3;   // 256/8 = 32
  flat = (flat & 7) * cpx + (flat >> 3);
  const int nbx = flat % gx;
  const int tq  = flat / gx;
  const int nby = tq % gy;
  const int nbz = tq / gy;

  const int tileM = nby * 256;
  const int tileN = nbx * 256;
  const int z = (KSPLIT > 1) ? nbz : 0;
  const int kBase = z * (K / KSPLIT);
  const int iters = (K / KSPLIT) / BK;
  float* Cf = (z == 0) ? P0 : (z == 1) ? P1 : (z == 2) ? P2 : P3;

  const int rr = t >> 2;               // staging row within a 128-row group
  const int cc = t & 3;                // fixed LDS 16B-slot index

  const int lane = t & 63;
  const int wave = t >> 6;
  const int wm = wave >> 1;            // 4x2 wave grid, wave tile 64x128
  const int wn = wave & 1;
  const int lr = lane & 15;
  const int kqc = lane >> 4;           // fragment k-chunk (16B units)

  f32x4 acc[4][8] = {};

  // stage full tile into buffer (8 gld16 per thread, wave-uniform linear dest)
  auto stage = [&](int buf, int k0) {
#pragma unroll
    for (int p = 0; p < 2; ++p) {
      const int r = p * 128 + rr;
      const int q = cc ^ ((r >> 1) & 3);  // swizzle via global addr
      const size_t ga = (size_t)(tileM + r) * K + k0 + q * 8;
      const size_t gb = (size_t)(tileN + r) * K + k0 + q * 8;
      const int ls = r * BK + cc * 8;     // == wave_base + lane*16 bytes
      gld16(Ahi + ga, &sA[buf][0][ls]);
      gld16(Alo + ga, &sA[buf][1][ls]);
      gld16(Bhi + gb, &sB[buf][0][ls]);
      gld16(Blo + gb, &sB[buf][1][ls]);
    }
  };

  stage(0, kBase);

  for (int it = 0; it < iters; ++it) {
    const int buf = it & 1;

    if (it + 1 < iters) {
      stage(buf ^ 1, kBase + (it + 1) * BK);
      __builtin_amdgcn_s_waitcnt(WAIT_VM8);  // oldest 8 (= this tile) done
    } else {
      __builtin_amdgcn_s_waitcnt(WAIT_VM0);
    }
    __builtin_amdgcn_s_barrier();            // all waves staged buf

    bf16x8 ah[4], al[4];
    auto loadA = [&](int mi) {
      const int R = wm * 64 + mi * 16 + lr;
      const int off = R * BK + (kqc ^ ((R >> 1) & 3)) * 8;
      ah[mi] = *(const bf16x8*)&sA[buf][0][off];
      al[mi] = *(const bf16x8*)&sA[buf][1][off];
    };
    bf16x8 bh[2], bl[2];                 // register B double-buffer
    auto loadB = [&](int nj, int par) {
      const int R = wn * 128 + nj * 16 + lr;
      const int off = R * BK + (kqc ^ ((R >> 1) & 3)) * 8;
      bh[par] = *(const bf16x8*)&sB[buf][0][off];
      bl[par] = *(const bf16x8*)&sB[buf][1][off];
    };
    auto mfma3 = [&](int mi, int nj, int par) {
      f32x4 a = acc[mi][nj];
      a = __builtin_amdgcn_mfma_f32_16x16x32_bf16(ah[mi], bh[par], a, 0, 0, 0);
      a = __builtin_amdgcn_mfma_f32_16x16x32_bf16(ah[mi], bl[par], a, 0, 0, 0);
      a = __builtin_amdgcn_mfma_f32_16x16x32_bf16(al[mi], bh[par], a, 0, 0, 0);
      acc[mi][nj] = a;
    };

    // just-in-time reads: 6 b128 before the first MFMA group, the rest
    // issued between MFMA groups so LDS service overlaps the matrix pipe.
    loadA(0); loadA(1);
    loadB(0, 0);
    mfma3(0, 0, 0); mfma3(1, 0, 0);
    loadA(2); loadA(3);
    loadB(1, 1);
    mfma3(2, 0, 0); mfma3(3, 0, 0);
#pragma unroll
    for (int nj = 1; nj < 8; ++nj) {
      const int par = nj & 1;
      if (nj < 7) loadB(nj + 1, par ^ 1);
      mfma3(0, nj, par); mfma3(1, nj, par);
      mfma3(2, nj, par); mfma3(3, nj, par);
    }

    __builtin_amdgcn_s_waitcnt(WAIT_LGKM0);  // frag reads landed in regs
    __builtin_amdgcn_s_barrier();            // safe to overwrite buf next iter
  }

  // epilogue: C/D layout col=lane&15, row=(lane>>4)*4+reg
#pragma unroll
  for (int mi = 0; mi < 4; ++mi)
#pragma unroll
    for (int ni = 0; ni < 8; ++ni)
#pragma unroll
      for (int e = 0; e < 4; ++e) {
        const int row = tileM + wm * 64 + mi * 16 + (lane >> 4) * 4 + e;
        const int col = tileN + wn * 128 + ni * 16 + lr;
        Cf[(size_t)row * N + col] = acc[mi][ni][e];
      }
}

// ------- in-place row softmax over 4096 columns, fusing the p0+p1 add -------
__global__ __launch_bounds__(256) void softmax_rows2(
    float* __restrict__ d, const float* __restrict__ p1, int cols) {
  const int row = blockIdx.x;
  float* p = d + (size_t)row * cols;
  const float* q = p1 + (size_t)row * cols;
  const int t = threadIdx.x;
  const int lane = t & 63;
  const int wave = t >> 6;
  __shared__ float sred[4];

  float4 v[4];
  float m = -3.0e38f;
#pragma unroll
  for (int k = 0; k < 4; ++k) {
    float4 a = *(const float4*)&p[(t + k * 256) * 4];
    float4 b = *(const float4*)&q[(t + k * 256) * 4];
    a.x += b.x; a.y += b.y; a.z += b.z; a.w += b.w;
    v[k] = a;
    m = fmaxf(m, fmaxf(fmaxf(a.x, a.y), fmaxf(a.z, a.w)));
  }
#pragma unroll
  for (int off = 32; off > 0; off >>= 1) m = fmaxf(m, __shfl_xor(m, off, 64));
  if (lane == 0) sred[wave] = m;
  __syncthreads();
  m = fmaxf(fmaxf(sred[0], sred[1]), fmaxf(sred[2], sred[3]));
  __syncthreads();

  float s = 0.f;
#pragma unroll
  for (int k = 0; k < 4; ++k) {
    v[k].x = __expf(v[k].x - m);
    v[k].y = __expf(v[k].y - m);
    v[k].z = __expf(v[k].z - m);
    v[k].w = __expf(v[k].w - m);
    s += (v[k].x + v[k].y) + (v[k].z + v[k].w);
  }
#pragma unroll
  for (int off = 32; off > 0; off >>= 1) s += __shfl_xor(s, off, 64);
  if (lane == 0) sred[wave] = s;
  __syncthreads();
  s = (sred[0] + sred[1]) + (sred[2] + sred[3]);
  const float inv = 1.0f / s;
#pragma unroll
  for (int k = 0; k < 4; ++k) {
    v[k].x *= inv; v[k].y *= inv; v[k].z *= inv; v[k].w *= inv;
    *(float4*)&p[(t + k * 256) * 4] = v[k];
  }
}

extern "C" void kernel_launch(void* const* d_in, const int* in_sizes, int n_in,
                              void* d_out, int out_size, void* d_ws, size_t ws_size,
                              hipStream_t stream) {
  const float* out_state = (const float*)d_in[0];  // [2048, 2048]
  const float* history   = (const float*)d_in[1];  // [4096, 2048]
  const float* W         = (const float*)d_in[2];  // [2048, 2048]
  // d_in[3] = b : softmax-invariant, unused.
  float* out = (float*)d_out;                      // [2048, 4096] fp32

  char* ws = (char*)d_ws;
  const size_t MB = 1ull << 20;
  unsigned short* ohi  = (unsigned short*)(ws + 0 * MB);   // 8 MB
  unsigned short* olo  = (unsigned short*)(ws + 8 * MB);   // 8 MB
  unsigned short* wthi = (unsigned short*)(ws + 16 * MB);  // 8 MB
  unsigned short* wtlo = (unsigned short*)(ws + 24 * MB);  // 8 MB
  unsigned short* hhi  = (unsigned short*)(ws + 32 * MB);  // 16 MB
  unsigned short* hlo  = (unsigned short*)(ws + 48 * MB);  // 16 MB
  float*          pws  = (float*)(ws + 64 * MB);           // 32 MB fp32 partials

  const size_t QSZ = (size_t)STATE_LEN * HIDDEN;           // 4M elems = 16 MB
  // GEMM1 partials: 2 in ws, 2 in d_out (d_out dead until GEMM2)
  float* g1p0 = pws;
  float* g1p1 = pws + QSZ;
  float* g1p2 = out;
  float* g1p3 = out + QSZ;
  // T split reuses ws[0:16] (os split dead after GEMM1)
  unsigned short* thi = (unsigned short*)(ws + 0 * MB);
  unsigned short* tlo = (unsigned short*)(ws + 8 * MB);

  // 1) all packing in one kernel: transpose W (1024 blocks, longest, FIRST) +
  //    split os (2048) + split hist (4096), 32B/thread
  pack_all<<<7168, 256, 0, stream>>>(out_state, history, W, ohi, olo, hhi, hlo,
                                     wthi, wtlo);
  // 2) T partials: 256x256 tiles, KSPLIT=4 -> 8x8x4 = 256 blocks (1/CU)
  gemm_big<4><<<dim3(HIDDEN / 256, STATE_LEN / 256, 4), 512, 0, stream>>>(
      ohi, olo, wthi, wtlo, g1p0, g1p1, g1p2, g1p3, STATE_LEN, HIDDEN, HIDDEN);
  // 3) T = p0+p1+p2+p3 -> split bf16
  reduce_split4<<<(STATE_LEN * HIDDEN) / 1024, 256, 0, stream>>>(
      g1p0, g1p1, g1p2, g1p3, thi, tlo, STATE_LEN * HIDDEN);
  // 4) scores partials: KSPLIT=2 -> 16x8x2 = 256 blocks; z=0 -> d_out,
  //    z=1 -> pws (GEMM1 ws-partials dead after reduce)
  gemm_big<2><<<dim3(SEQ_LEN / 256, STATE_LEN / 256, 2), 512, 0, stream>>>(
      thi, tlo, hhi, hlo, out, pws, nullptr, nullptr, STATE_LEN, SEQ_LEN, HIDDEN);
  // 5) row softmax in place, fusing the partial add
  softmax_rows2<<<STATE_LEN, 256, 0, stream>>>(out, pws, SEQ_LEN);
}